// Round 2
// baseline (402.639 us; speedup 1.0000x reference)
//
#include <hip/hip_runtime.h>
#include <stdint.h>

#define T_LEN 512
#define EMBD  32
#define HIDN  32
#define GW    128   // 4*HID gate columns
#define VOCAB 101
#define GP    132   // G table pitch (bf16 elems per vocab row), [v][unit][gate] interleaved
#define SP    132   // S pitch in f32 per batch row, [row][unit][gate] interleaved
#define HP    40    // hA pitch in bf16 (padded from 32)
#define XP    68    // x tile pitch in int (padded from 64, 16B-aligned rows)

typedef short short8 __attribute__((ext_vector_type(8)));
typedef float f32x4  __attribute__((ext_vector_type(4)));

__device__ __forceinline__ float bf2f(uint16_t u) {
    union { uint32_t i; float f; } x; x.i = ((uint32_t)u) << 16; return x.f;
}
__device__ __forceinline__ uint16_t f2bf(float f) {
    union { float f; uint32_t i; } x; x.f = f;
    return (uint16_t)((x.i + 0x7FFFu + ((x.i >> 16) & 1u)) >> 16);
}
__device__ __forceinline__ float asF(uint32_t u) {
    union { uint32_t i; float f; } x; x.i = u; return x.f;
}
__device__ __forceinline__ float sigm(float x) {
    return __builtin_amdgcn_rcpf(1.f + __expf(-x));
}
__device__ __forceinline__ float tanh_f(float x) {
    // tanh(x) = 1 - 2/(exp(2x)+1); preacts are O(1), no overflow risk
    return 1.f - 2.f * __builtin_amdgcn_rcpf(__expf(2.f * x) + 1.f);
}
// dual-dtype weight load: buffers may be bf16 (harness bf16 mode) or f32 (reference dtype)
__device__ __forceinline__ float getw(const void* p, int i, bool isbf) {
    return isbf ? bf2f(((const uint16_t*)p)[i]) : ((const float*)p)[i];
}
// Detect bf16 vs f32 from bit patterns: bf16 arrays have sane exponents in every
// 16-bit word; f32 arrays read as uint16 have garbage exponents in the low halves.
__device__ __forceinline__ bool detect_bf16(const void* embp) {
    const uint16_t* u = (const uint16_t*)embp;
    int sane = 0;
    for (int i = 0; i < 64; ++i) {
        uint16_t v = u[i];
        int e = (v >> 7) & 0xFF;
        sane += ((e >= 100 && e <= 140) || ((v & 0x7FFFu) == 0)) ? 1 : 0;
    }
    return sane >= 56;
}

__global__ __launch_bounds__(256) void lstm_fused(
    const int* __restrict__ x, const void* __restrict__ emb,
    const void* __restrict__ Wx, const void* __restrict__ Wh,
    const void* __restrict__ bias, const void* __restrict__ Wfc,
    const void* __restrict__ bfc, void* __restrict__ out)
{
    __shared__ __align__(16) uint16_t G_l[VOCAB * GP];  // 26,664 B  bf16 xg table, gate-interleaved
    __shared__ __align__(16) float    S_l[16 * SP];     //  8,448 B  h@Wh preacts, gate-interleaved
    __shared__ __align__(16) uint16_t hA[16 * HP];      //  1,280 B  h in MFMA A-layout [row][k]
    __shared__ __align__(16) int      xt[16 * XP];      //  4,352 B  x tile [row][64 steps]

    const int tid = threadIdx.x;
    const int wl  = tid & 63;        // lane within wave
    const int w   = tid >> 6;        // wave id 0..3
    const int n   = wl & 15;         // MFMA n / m index
    const int q   = wl >> 4;         // MFMA k-quad
    const int b0  = blockIdx.x * 16; // batch base for this block

    const bool isbf = detect_bf16(emb);  // uniform across all threads

    // ---- stage emb as bf16 into S_l scratch ----
    {
        uint16_t* embL = (uint16_t*)S_l;
        for (int i = tid; i < VOCAB * EMBD; i += 256)
            embL[i] = isbf ? ((const uint16_t*)emb)[i] : f2bf(((const float*)emb)[i]);
    }
    __syncthreads();
    // ---- build G table: G[v][col] = emb[v]@Wx + b, stored bf16 gate-interleaved ----
    {
        const uint16_t* embL = (const uint16_t*)S_l;
        for (int idx = tid; idx < VOCAB * GW; idx += 256) {
            int v = idx >> 7, col = idx & 127;
            float acc = getw(bias, col, isbf);
            #pragma unroll 8
            for (int k = 0; k < EMBD; ++k)
                acc += bf2f(embL[v * EMBD + k]) * getw(Wx, k * GW + col, isbf);
            G_l[v * GP + ((col & 31) << 2) + (col >> 5)] = f2bf(acc);
        }
    }
    // ---- zero h (A-layout buffer) ----
    for (int i = tid; i < 16 * HP / 2; i += 256) ((uint32_t*)hA)[i] = 0u;
    __syncthreads();

    // ---- load B fragments: Wh[k][col], wave w owns col tiles {16w..16w+15, 64+16w..64+16w+15} ----
    short8 bfr0, bfr1;
    {
        union { short8 v; uint16_t s[8]; } u0, u1;
        int c0 = w * 16 + n;
        int c1 = (w + 4) * 16 + n;
        #pragma unroll
        for (int j = 0; j < 8; ++j) {
            int k = q * 8 + j;
            u0.s[j] = f2bf(getw(Wh, k * GW + c0, isbf));
            u1.s[j] = f2bf(getw(Wh, k * GW + c1, isbf));
        }
        bfr0 = u0.v; bfr1 = u1.v;
    }
    // S-write slots (gate-interleaved): col -> unit*4 + gate
    const int col0 = w * 16 + n;
    const int col1 = (w + 4) * 16 + n;
    const int sw0 = ((col0 & 31) << 2) + (col0 >> 5);
    const int sw1 = ((col1 & 31) << 2) + (col1 >> 5);

    // phase-B mapping: thread -> (batch row, unit pair)
    const int prow = tid & 15;
    const int u0i  = (tid >> 4) << 1;   // 0,2,..,30
    float c0v = 0.f, c1v = 0.f;

    for (int t = 0; t < T_LEN; ++t) {
        if ((t & 63) == 0) {
            // stage next 64 timesteps of x (prev end-of-step barrier ordered old reads)
            int r = tid >> 4, cc = (tid & 15) << 2;
            int4 vv = *(const int4*)&x[(b0 + r) * T_LEN + t + cc];
            *(int4*)&xt[r * XP + cc] = vv;
            // consumed only in phase B, after the mid-step barrier
        }
        // ---- phase A: S = h @ Wh via MFMA, scatter C-layout into S_l ----
        short8 af = *(const short8*)&hA[n * HP + q * 8];
        f32x4 acc0 = {0.f, 0.f, 0.f, 0.f};
        f32x4 acc1 = {0.f, 0.f, 0.f, 0.f};
        acc0 = __builtin_amdgcn_mfma_f32_16x16x32_bf16(af, bfr0, acc0, 0, 0, 0);
        acc1 = __builtin_amdgcn_mfma_f32_16x16x32_bf16(af, bfr1, acc1, 0, 0, 0);
        #pragma unroll
        for (int r = 0; r < 4; ++r) {
            int row = q * 4 + r;          // C/D: col=lane&15, row=(lane>>4)*4+reg
            S_l[row * SP + sw0] = acc0[r];
            S_l[row * SP + sw1] = acc1[r];
        }
        __syncthreads();
        // ---- phase B: preact = S + G[x], gates, state update, write h in A-layout ----
        {
            int v = xt[prow * XP + (t & 63)];
            const uint32_t* gp = (const uint32_t*)&G_l[v * GP + (u0i << 2)];
            const float* sp = &S_l[prow * SP + (u0i << 2)];
            f32x4 s0 = *(const f32x4*)sp;
            f32x4 s1 = *(const f32x4*)(sp + 4);
            uint32_t g01 = gp[0], g23 = gp[1], g45 = gp[2], g67 = gp[3];
            float pi0 = s0[0] + asF(g01 << 16);
            float pf0 = s0[1] + asF(g01 & 0xFFFF0000u);
            float pg0 = s0[2] + asF(g23 << 16);
            float po0 = s0[3] + asF(g23 & 0xFFFF0000u);
            float pi1 = s1[0] + asF(g45 << 16);
            float pf1 = s1[1] + asF(g45 & 0xFFFF0000u);
            float pg1 = s1[2] + asF(g67 << 16);
            float po1 = s1[3] + asF(g67 & 0xFFFF0000u);
            c0v = sigm(pf0) * c0v + sigm(pi0) * tanh_f(pg0);
            c1v = sigm(pf1) * c1v + sigm(pi1) * tanh_f(pg1);
            float h0 = sigm(po0) * tanh_f(c0v);
            float h1 = sigm(po1) * tanh_f(c1v);
            *(uint32_t*)&hA[prow * HP + u0i] =
                (uint32_t)f2bf(h0) | ((uint32_t)f2bf(h1) << 16);
        }
        __syncthreads();
    }

    // ---- epilogue: out = h_last @ W_fc + b_fc ----
    if (tid < 32) {
        int row = tid >> 1, cc = tid & 1;
        float acc = getw(bfc, cc, isbf);
        #pragma unroll 8
        for (int k = 0; k < HIDN; ++k)
            acc += bf2f(hA[row * HP + k]) * getw(Wfc, k * 2 + cc, isbf);
        int oidx = (b0 + row) * 2 + cc;
        if (isbf) ((uint16_t*)out)[oidx] = f2bf(acc);
        else      ((float*)out)[oidx]    = acc;
    }
}

extern "C" void kernel_launch(void* const* d_in, const int* in_sizes, int n_in,
                              void* d_out, int out_size, void* d_ws, size_t ws_size,
                              hipStream_t stream) {
    (void)in_sizes; (void)n_in; (void)d_ws; (void)ws_size; (void)out_size;
    const int* x = (const int*)d_in[0];
    lstm_fused<<<dim3(256), dim3(256), 0, stream>>>(
        x, d_in[1], d_in[2], d_in[3], d_in[4], d_in[5], d_in[6], d_out);
}

// Round 3
// 318.001 us; speedup vs baseline: 1.2662x; 1.2662x over previous
//
#include <hip/hip_runtime.h>
#include <stdint.h>

#define T_LEN 512
#define HIDN  32
#define GW    128
#define VOCAB 101
#define GP    132   // G pitch (bf16/row), layout [v][unit*4+gate], gate order i,f,g,o
#define HP    56    // h pitch in bf16 (16B-aligned rows, ~2-way max conflict on b128)
#define XPB   516   // packed-u8 x pitch in bytes (129 words: odd*? -> bank spread)

typedef short short8 __attribute__((ext_vector_type(8)));
typedef float f32x4  __attribute__((ext_vector_type(4)));

#define LOG2E 1.442695041f

__device__ __forceinline__ float bf2f(uint16_t u) {
    union { uint32_t i; float f; } x; x.i = ((uint32_t)u) << 16; return x.f;
}
__device__ __forceinline__ uint16_t f2bf(float f) {
    union { float f; uint32_t i; } x; x.f = f;
    return (uint16_t)((x.i + 0x7FFFu + ((x.i >> 16) & 1u)) >> 16);
}
__device__ __forceinline__ float asF(uint32_t u) {
    union { uint32_t i; float f; } x; x.i = u; return x.f;
}
__device__ __forceinline__ float bf_lo(uint32_t u) { return asF(u << 16); }
__device__ __forceinline__ float bf_hi(uint32_t u) { return asF(u & 0xFFFF0000u); }
// preacts arrive PRE-SCALED by log2(e): sigm(x) = 1/(1+exp2(-x'))
__device__ __forceinline__ float sigm2(float xs) {
    return __builtin_amdgcn_rcpf(1.f + __builtin_amdgcn_exp2f(-xs));
}
// tanh from pre-scaled y' = log2e*y : tanh(y) = 1 - 2/(exp2(2y')+1)
__device__ __forceinline__ float tanh2s(float ys) {
    return 1.f - 2.f * __builtin_amdgcn_rcpf(__builtin_amdgcn_exp2f(ys + ys) + 1.f);
}
// tanh of a TRUE-scale value (cell state)
__device__ __forceinline__ float tanh2t(float y) {
    return 1.f - 2.f * __builtin_amdgcn_rcpf(__builtin_amdgcn_exp2f(2.885390082f * y) + 1.f);
}
__device__ __forceinline__ float getw(const void* p, int i, bool isbf) {
    return isbf ? bf2f(((const uint16_t*)p)[i]) : ((const float*)p)[i];
}
__device__ __forceinline__ bool detect_bf16(const void* embp) {
    const uint16_t* u = (const uint16_t*)embp;
    int sane = 0;
    for (int i = 0; i < 64; ++i) {
        uint16_t v = u[i];
        int e = (v >> 7) & 0xFF;
        sane += ((e >= 100 && e <= 140) || ((v & 0x7FFFu) == 0)) ? 1 : 0;
    }
    return sane >= 56;
}

__global__ __launch_bounds__(256) void lstm_fused(
    const int* __restrict__ x, const void* __restrict__ emb,
    const void* __restrict__ Wx, const void* __restrict__ Wh,
    const void* __restrict__ bias, const void* __restrict__ Wfc,
    const void* __restrict__ bfc, void* __restrict__ out)
{
    __shared__ __align__(16) uint16_t G_l[VOCAB * GP];   // 26,664 B
    __shared__ __align__(16) uint8_t  xt8[16 * XPB];     //  8,256 B (emb scratch at init)
    __shared__ __align__(16) uint16_t hbuf[2 * 16 * HP]; //  3,584 B double-buffered h

    const int tid = threadIdx.x;
    const int wl  = tid & 63;
    const int w   = tid >> 6;       // wave 0..3 -> owns units 8w..8w+7
    const int n   = wl & 15;        // batch row within group (MFMA n / A-m index)
    const int q   = wl >> 4;        // MFMA k-quad
    const int b0  = blockIdx.x * 16;

    const bool isbf = detect_bf16(emb);

    // ---- stage emb (bf16) into xt8 scratch ----
    {
        uint16_t* embL = (uint16_t*)xt8;
        for (int i = tid; i < VOCAB * 32; i += 256)
            embL[i] = isbf ? ((const uint16_t*)emb)[i] : f2bf(((const float*)emb)[i]);
    }
    __syncthreads();
    // ---- build G: G[v][u*4+g] = log2e * (emb[v]@Wx + b)[32g+u], bf16 ----
    {
        const uint16_t* embL = (const uint16_t*)xt8;
        for (int idx = tid; idx < VOCAB * GW; idx += 256) {
            int v = idx >> 7, col = idx & 127;
            float acc = getw(bias, col, isbf);
            #pragma unroll 8
            for (int k = 0; k < 32; ++k)
                acc += bf2f(embL[v * 32 + k]) * getw(Wx, k * GW + col, isbf);
            G_l[v * GP + ((col & 31) << 2) + (col >> 5)] = f2bf(acc * LOG2E);
        }
    }
    __syncthreads();   // emb scratch dead; xt8 reusable
    // ---- pack x tokens to u8 for all 512 steps ----
    for (int i = tid; i < 2048; i += 256) {         // 16 rows * 128 int4
        int row = i >> 7, c4 = i & 127;
        int4 vv = *(const int4*)&x[(b0 + row) * T_LEN + (c4 << 2)];
        uint32_t p = (uint32_t)(vv.x & 255) | ((uint32_t)(vv.y & 255) << 8) |
                     ((uint32_t)(vv.z & 255) << 16) | ((uint32_t)(vv.w & 255) << 24);
        ((uint32_t*)&xt8[row * XPB])[c4] = p;
    }
    // ---- zero h buffers ----
    for (int i = tid; i < 2 * 16 * HP; i += 256) hbuf[i] = 0;

    // ---- A-fragments: A_j[m=n][k=8q+jj] = log2e * Wh[8q+jj][32*(n&3) + 4*jt + (n>>2)]
    //      tile jt covers units 4jt..4jt+3, permuted col = unit-local*4 + gate ----
    short8 afr0, afr1;
    {
        union { short8 v; uint16_t s[8]; } u0, u1;
        int oc0 = 32 * (n & 3) + 4 * (2 * w)     + (n >> 2);
        int oc1 = 32 * (n & 3) + 4 * (2 * w + 1) + (n >> 2);
        #pragma unroll
        for (int jj = 0; jj < 8; ++jj) {
            int k = 8 * q + jj;
            u0.s[jj] = f2bf(getw(Wh, k * GW + oc0, isbf) * LOG2E);
            u1.s[jj] = f2bf(getw(Wh, k * GW + oc1, isbf) * LOG2E);
        }
        afr0 = u0.v; afr1 = u1.v;
    }
    __syncthreads();

    const int u0i = 8 * w + q;       // lane's unit from tile 2w
    const int u1i = 8 * w + 4 + q;   // lane's unit from tile 2w+1
    float c0 = 0.f, c1 = 0.f;

    // prefetch G for t=0
    uint32_t gA0, gA1, gB0, gB1;
    {
        int v = xt8[n * XPB];
        const uint32_t* g = (const uint32_t*)&G_l[v * GP];
        gA0 = g[u0i * 2]; gA1 = g[u0i * 2 + 1];
        gB0 = g[u1i * 2]; gB1 = g[u1i * 2 + 1];
    }

    for (int t = 0; t < T_LEN; ++t) {
        const uint16_t* hr = &hbuf[(t & 1) * (16 * HP)];
        uint16_t*       hw = &hbuf[((t & 1) ^ 1) * (16 * HP)];
        // B fragment: h(t-1)[n][8q..8q+7]
        short8 bfrag = *(const short8*)&hr[n * HP + 8 * q];
        f32x4 s0 = {0.f, 0.f, 0.f, 0.f};
        f32x4 s1 = {0.f, 0.f, 0.f, 0.f};
        s0 = __builtin_amdgcn_mfma_f32_16x16x32_bf16(afr0, bfrag, s0, 0, 0, 0);
        s1 = __builtin_amdgcn_mfma_f32_16x16x32_bf16(afr1, bfrag, s1, 0, 0, 0);
        // prefetch G for t+1 (depends only on x -> overlaps MFMA latency)
        int vn = xt8[n * XPB + ((t + 1) & (T_LEN - 1))];
        const uint32_t* gnx = (const uint32_t*)&G_l[vn * GP];
        uint32_t nA0 = gnx[u0i * 2], nA1 = gnx[u0i * 2 + 1];
        uint32_t nB0 = gnx[u1i * 2], nB1 = gnx[u1i * 2 + 1];
        // gates, unit0 (acc regs r = i,f,g,o)
        {
            float pi = s0[0] + bf_lo(gA0), pf = s0[1] + bf_hi(gA0);
            float pg = s0[2] + bf_lo(gA1), po = s0[3] + bf_hi(gA1);
            c0 = sigm2(pf) * c0 + sigm2(pi) * tanh2s(pg);
            hw[n * HP + u0i] = f2bf(sigm2(po) * tanh2t(c0));
        }
        // gates, unit1
        {
            float pi = s1[0] + bf_lo(gB0), pf = s1[1] + bf_hi(gB0);
            float pg = s1[2] + bf_lo(gB1), po = s1[3] + bf_hi(gB1);
            c1 = sigm2(pf) * c1 + sigm2(pi) * tanh2s(pg);
            hw[n * HP + u1i] = f2bf(sigm2(po) * tanh2t(c1));
        }
        gA0 = nA0; gA1 = nA1; gB0 = nB0; gB1 = nB1;
        __syncthreads();   // no VMEM in flight -> cheap drain (lgkm only)
    }

    // ---- epilogue: out = h(T-1) @ W_fc + b_fc ; h(511) lives in buf 0 ----
    if (tid < 32) {
        int row = tid >> 1, cc = tid & 1;
        float acc = getw(bfc, cc, isbf);
        #pragma unroll 8
        for (int k = 0; k < HIDN; ++k)
            acc += bf2f(hbuf[row * HP + k]) * getw(Wfc, k * 2 + cc, isbf);
        int oidx = (b0 + row) * 2 + cc;
        if (isbf) ((uint16_t*)out)[oidx] = f2bf(acc);
        else      ((float*)out)[oidx]    = acc;
    }
}

extern "C" void kernel_launch(void* const* d_in, const int* in_sizes, int n_in,
                              void* d_out, int out_size, void* d_ws, size_t ws_size,
                              hipStream_t stream) {
    (void)in_sizes; (void)n_in; (void)d_ws; (void)ws_size; (void)out_size;
    const int* x = (const int*)d_in[0];
    lstm_fused<<<dim3(256), dim3(256), 0, stream>>>(
        x, d_in[1], d_in[2], d_in[3], d_in[4], d_in[5], d_in[6], d_out);
}